// Round 8
// baseline (255.677 us; speedup 1.0000x reference)
//
#include <hip/hip_runtime.h>

typedef unsigned short u16;
typedef float f2 __attribute__((ext_vector_type(2)));

#define NQ 14
#define NSTATE (1 << NQ)   // 16384
#define DEPTH 8
#define TPB 1024

// ---------- host-side constants passed by value ----------
struct PassK {
  u16 cm[3];       // cross masks: lane^1, lane^2, lane^8
  u16 srow[7];     // sign rows of L: slots 0..3 in-reg, 4..6 cross
  u16 scol[7];     // complement basis: t bit 2 -> scol[0]; t bits 4..9 -> scol[1..6]
  u16 widx[7];     // within-layer theta index per slot (0..13)
  u16 xm[16];      // XOR combos of the 4 in-register pair masks
};

struct SimConsts {
  PassK pass[7][2];   // layers 1..7 x two 7-wire passes
  u16 zrow[14];       // rows of L_8 for <Z_w> sign
  u16 zfreq[14];      // 4-bit WHT frequency per wire (layer-7 pass-2 mask basis)
};

// ---------- device ----------
__device__ __forceinline__ f2 cmulv(f2 a, f2 b) {
  f2 r;
  r.x = a.x * b.x - a.y * b.y;
  r.y = a.x * b.y + a.y * b.x;
  return r;
}

template <int CTRL>
__device__ __forceinline__ f2 dpp_f2(f2 v) {
  f2 r;
  r.x = __int_as_float(
      __builtin_amdgcn_mov_dpp(__float_as_int(v.x), CTRL, 0xf, 0xf, true));
  r.y = __int_as_float(
      __builtin_amdgcn_mov_dpp(__float_as_int(v.y), CTRL, 0xf, 0xf, true));
  return r;
}

// 7-wire RY pass: 4 wires in-register + 3 wires via DPP (lane^1, lane^2, lane^8).
// If !WRITE, leaves results in a[] and repx in *repx_out (caller finishes).
template <bool USE_WS, bool WRITE>
__device__ __forceinline__ void ry7x(f2* st, const PassK& P, const float* th,
                                     const float2* ttd, int t,
                                     f2* a, unsigned* repx_out) {
  unsigned rep = ((t >> 2) & 1u) ? (unsigned)P.scol[0] : 0u;
  #pragma unroll
  for (int b = 1; b < 7; ++b)
    rep ^= ((t >> (3 + b)) & 1u) ? (unsigned)P.scol[b] : 0u;   // t bits 4..9
  unsigned repx = rep ^ ((t & 1) ? (unsigned)P.cm[0] : 0u)
                      ^ ((t & 2) ? (unsigned)P.cm[1] : 0u)
                      ^ ((t & 8) ? (unsigned)P.cm[2] : 0u);
  *repx_out = repx;

  float c[7], ss[7];
  #pragma unroll
  for (int i = 0; i < 7; ++i) {
    if constexpr (USE_WS) {
      float2 tv = ttd[P.widx[i]];      // uniform -> s_load
      c[i] = tv.x; ss[i] = tv.y;
    } else {
      __sincosf(0.5f * th[P.widx[i]], &ss[i], &c[i]);
    }
  }
  float sa[4];
  #pragma unroll
  for (int i = 0; i < 4; ++i)
    sa[i] = (__popc((unsigned)P.srow[i] & rep) & 1) ? -ss[i] : ss[i];
  const float sg4 =
      ((__popc((unsigned)P.srow[4] & rep) ^ t) & 1) ? ss[4] : -ss[4];
  const float sg5 =
      ((__popc((unsigned)P.srow[5] & rep) ^ (t >> 1)) & 1) ? ss[5] : -ss[5];
  const float sg6 =
      ((__popc((unsigned)P.srow[6] & rep) ^ (t >> 3)) & 1) ? ss[6] : -ss[6];

  const unsigned base = repx << 3;
  unsigned ad[16];
  #pragma unroll
  for (int e = 0; e < 16; ++e)
    ad[e] = base ^ (((unsigned)P.xm[e]) << 3);   // xm<<3 uniform (SGPR)

  #pragma unroll
  for (int e = 0; e < 16; ++e) a[e] = *(const f2*)((const char*)st + ad[e]);

  // cross slot 4: partner = lane^1 (quad_perm [1,0,3,2])
  {
    const float c4 = c[4];
    #pragma unroll
    for (int e = 0; e < 16; ++e) {
      f2 p = dpp_f2<0xB1>(a[e]);
      a[e] = c4 * a[e] + sg4 * p;
    }
  }
  // 4 in-register wires
  #pragma unroll
  for (int i = 0; i < 4; ++i) {
    const float ci = c[i], si = sa[i];
    #pragma unroll
    for (int e = 0; e < 16; ++e) {
      if (!(e & (1 << i))) {
        f2 xe = a[e], ye = a[e | (1 << i)];
        a[e]            = ci * xe - si * ye;
        a[e | (1 << i)] = si * xe + ci * ye;
      }
    }
  }
  // cross slot 5: partner = lane^2 (quad_perm [2,3,0,1])
  {
    const float c5 = c[5];
    #pragma unroll
    for (int e = 0; e < 16; ++e) {
      f2 p = dpp_f2<0x4E>(a[e]);
      a[e] = c5 * a[e] + sg5 * p;
    }
  }
  // cross slot 6: partner = lane^8 (row_ror:8 on 16-lane rows == XOR 8)
  {
    const float c6 = c[6];
    #pragma unroll
    for (int e = 0; e < 16; ++e) {
      f2 p = dpp_f2<0x128>(a[e]);
      a[e] = c6 * a[e] + sg6 * p;
    }
  }

  if constexpr (WRITE) {
    #pragma unroll
    for (int e = 0; e < 16; ++e) *(f2*)((char*)st + ad[e]) = a[e];
  }
}

template <bool USE_WS>
__global__ __launch_bounds__(TPB, 1) void qsim_kernel(
    const float* __restrict__ inp, const float* __restrict__ theta,
    float* __restrict__ out, const float2* __restrict__ tt,
    const float4* __restrict__ albe, int use_albe, SimConsts C) {
  __shared__ f2 st[NSTATE];   // 128 KiB
  const int s = blockIdx.x;
  const int t = threadIdx.x;

  // ---- init: product state after RX(inp) then RY(theta layer 0)
  f2 A[NQ], B[NQ];
  if constexpr (USE_WS) {
    if (use_albe) {
      #pragma unroll
      for (int w = 0; w < NQ; ++w) {
        float4 v = albe[s * NQ + w];       // uniform -> s_load_dwordx4
        A[w].x = v.x; A[w].y = v.y;
        B[w].x = v.z; B[w].y = v.w;
      }
    } else {
      #pragma unroll
      for (int w = 0; w < NQ; ++w) {
        float sx, cx; __sincosf(0.5f * inp[s * NQ + w], &sx, &cx);
        float2 tv = tt[w];
        A[w].x = tv.x * cx; A[w].y = tv.y * sx;
        B[w].x = tv.y * cx; B[w].y = -tv.x * sx;
      }
    }
  } else {
    #pragma unroll
    for (int w = 0; w < NQ; ++w) {
      float sx, cx; __sincosf(0.5f * inp[s * NQ + w], &sx, &cx);
      float stt, ctt; __sincosf(0.5f * theta[w], &stt, &ctt);
      A[w].x = ctt * cx; A[w].y = stt * sx;
      B[w].x = stt * cx; B[w].y = -ctt * sx;
    }
  }

  f2 a[16];
  {
    f2 rhi; rhi.x = 1.f; rhi.y = 0.f;
    #pragma unroll
    for (int b = 0; b < 10; ++b) {         // p bit b <- t bit b, wire 13-b
      const int w = 13 - b;
      f2 f = ((t >> b) & 1) ? B[w] : A[w];
      rhi = cmulv(rhi, f);
    }
    a[0] = rhi;
    #pragma unroll
    for (int k = 0; k < 4; ++k) {          // e bit k <-> p bit 10+k <-> wire 3-k
      const int w = 3 - k;
      const int sz = 1 << k;
      #pragma unroll
      for (int j = 0; j < 8; ++j) {
        if (j < sz) {
          f2 v = a[j];
          a[j]      = cmulv(v, A[w]);
          a[j + sz] = cmulv(v, B[w]);
        }
      }
    }
    #pragma unroll
    for (int e = 0; e < 16; ++e) st[(e << 10) | t] = a[e];
  }
  __syncthreads();

  // ---- layers 1..7, two 7-wire passes each (CNOT rings in the linear maps)
  unsigned repx;
  #pragma unroll 1
  for (int d = 1; d <= 6; ++d) {
    const float* th = theta + d * NQ;
    const float2* ttd = USE_WS ? (tt + d * NQ) : nullptr;
    ry7x<USE_WS, true>(st, C.pass[d - 1][0], th, ttd, t, a, &repx);
    __syncthreads();
    ry7x<USE_WS, true>(st, C.pass[d - 1][1], th, ttd, t, a, &repx);
    __syncthreads();
  }
  {
    const float* th = theta + 7 * NQ;
    const float2* ttd = USE_WS ? (tt + 7 * NQ) : nullptr;
    ry7x<USE_WS, true>(st, C.pass[6][0], th, ttd, t, a, &repx);
    __syncthreads();
    // last pass: keep results in registers, fuse measurement
    ry7x<USE_WS, false>(st, C.pass[6][1], th, ttd, t, a, &repx);
  }
  __syncthreads();   // all reads of the final pass done before st is reused

  // ---- measurement: per-thread |amp|^2, 4-bit WHT in mask basis
  float pv[16];
  #pragma unroll
  for (int e = 0; e < 16; ++e) pv[e] = a[e].x * a[e].x + a[e].y * a[e].y;
  #pragma unroll
  for (int s4 = 0; s4 < 4; ++s4) {
    const int step = 1 << s4;
    #pragma unroll
    for (int e = 0; e < 16; ++e) {
      if (!(e & step)) {
        float x = pv[e], y = pv[e | step];
        pv[e] = x + y; pv[e | step] = x - y;
      }
    }
  }
  float* stf = (float*)st;
  #pragma unroll
  for (int e = 0; e < 16; ++e) stf[(e << 10) | t] = pv[e];
  __syncthreads();

  float acc[NQ];
  #pragma unroll
  for (int w = 0; w < NQ; ++w) {
    const unsigned zf = (unsigned)C.zfreq[w];
    float v = stf[(zf << 10) | (unsigned)t];
    acc[w] = (__popc((unsigned)C.zrow[w] & repx) & 1) ? -v : v;
  }
  #pragma unroll
  for (int w = 0; w < NQ; ++w) {
    #pragma unroll
    for (int off = 32; off > 0; off >>= 1)
      acc[w] += __shfl_xor(acc[w], off, 64);
  }
  __syncthreads();
  const int lane = t & 63, wid = t >> 6;   // wid in 0..15
  if (lane == 0) {
    #pragma unroll
    for (int w = 0; w < NQ; ++w) stf[wid * NQ + w] = acc[w];
  }
  __syncthreads();
  if (t < NQ) {
    float tot = 0.f;
    #pragma unroll
    for (int k = 0; k < 16; ++k) tot += stf[k * NQ + t];
    out[s * NQ + t] = tot;
  }
}

// ---------- prep: precise trig tables into workspace ----------
__global__ void prep_kernel(const float* __restrict__ inp,
                            const float* __restrict__ theta,
                            float2* __restrict__ tt, float4* __restrict__ albe,
                            int nAlbe) {
  const int i = blockIdx.x * 256 + threadIdx.x;
  if (i < DEPTH * NQ) {
    float ss, cc; sincosf(0.5f * theta[i], &ss, &cc);
    tt[i] = make_float2(cc, ss);
  }
  if (albe != nullptr && i < nAlbe) {
    const int w = i % NQ;
    float sx, cx; sincosf(0.5f * inp[i], &sx, &cx);
    float stt, ctt; sincosf(0.5f * theta[w], &stt, &ctt);
    albe[i] = make_float4(ctt * cx, stt * sx, stt * cx, -ctt * sx);
  }
}

// ---------- host: GF(2) linear algebra for the CNOT-ring permutation ----------
static inline unsigned ffwd(unsigned x) {
  unsigned t = x;
  t ^= t >> 1; t ^= t >> 2; t ^= t >> 4; t ^= t >> 8;
  unsigned y = t & 0x1FFFu;
  y |= (((t >> 13) ^ t) & 1u) << 13;
  return y;
}
static inline unsigned finv(unsigned y) {
  unsigned x = 0;
  for (int j = 0; j <= 11; ++j) x |= (((y >> j) ^ (y >> (j + 1))) & 1u) << j;
  x |= (((y >> 12) ^ (y >> 13) ^ y) & 1u) << 12;
  x |= (((y >> 13) ^ y) & 1u) << 13;
  return x;
}
static inline int rank4(unsigned a, unsigned b, unsigned c) {
  unsigned bas[4] = {0, 0, 0, 0};
  unsigned vv[3] = {a & 15u, b & 15u, c & 15u};
  int r = 0;
  for (int i = 0; i < 3; ++i) {
    unsigned u = vv[i];
    for (int bit = 3; bit >= 0; --bit)
      if (((u >> bit) & 1u) && bas[bit]) u ^= bas[bit];
    if (u) { bas[31 - __builtin_clz(u)] = u; ++r; }
  }
  return r;
}

extern "C" void kernel_launch(void* const* d_in, const int* in_sizes, int n_in,
                              void* d_out, int out_size, void* d_ws, size_t ws_size,
                              hipStream_t stream) {
  const float* inp = (const float*)d_in[0];
  const float* theta = (const float*)d_in[1];
  float* out = (float*)d_out;
  const int batch = in_sizes[0] / NQ;

  SimConsts C;
  u16 Lc[NQ], Kc[NQ];   // columns of L = F^d and K = L^-1
  u16 mk2last[4] = {0, 0, 0, 0};   // in-reg masks of layer-7 pass-2
  for (int j = 0; j < NQ; ++j) { Lc[j] = (u16)(1u << j); Kc[j] = (u16)(1u << j); }
  for (int d = 1; d <= 8; ++d) {
    u16 nL[NQ], nK[NQ];
    for (int j = 0; j < NQ; ++j) nL[j] = (u16)ffwd((unsigned)Lc[j]);
    for (int j = 0; j < NQ; ++j) {
      unsigned fj = finv(1u << j);
      unsigned v = 0;
      for (int b = 0; b < NQ; ++b) if ((fj >> b) & 1u) v ^= Kc[b];
      nK[j] = (u16)v;
    }
    for (int j = 0; j < NQ; ++j) { Lc[j] = nL[j]; Kc[j] = nK[j]; }

    if (d <= 7) {
      for (int pg = 0; pg < 2; ++pg) {
        const int wbase = pg * 7;
        PassK& P = C.pass[d - 1][pg];

        // wire masks (K columns) and sign rows (L rows)
        u16 wmask[7]; unsigned wrow[7];
        for (int i = 0; i < 7; ++i) {
          const int bit = 13 - (wbase + i);
          wmask[i] = Kc[bit];
          unsigned r = 0;
          for (int j = 0; j < NQ; ++j) r |= ((unsigned)(Lc[j] >> bit) & 1u) << j;
          wrow[i] = r;
        }

        // pick cross triple maximizing low-nibble GF(2) rank
        int ca = 0, cb = 1, cc = 2, bestRank = -1;
        for (int x = 0; x < 7; ++x)
          for (int y = x + 1; y < 7; ++y)
            for (int z = y + 1; z < 7; ++z) {
              int r = rank4(wmask[x], wmask[y], wmask[z]);
              if (r > bestRank) { bestRank = r; ca = x; cb = y; cc = z; }
            }
        P.cm[0] = wmask[ca]; P.cm[1] = wmask[cb]; P.cm[2] = wmask[cc];
        P.srow[4] = (u16)wrow[ca]; P.srow[5] = (u16)wrow[cb]; P.srow[6] = (u16)wrow[cc];
        P.widx[4] = (u16)(wbase + ca); P.widx[5] = (u16)(wbase + cb);
        P.widx[6] = (u16)(wbase + cc);
        u16 mk[4]; int ii = 0;
        for (int i = 0; i < 7; ++i)
          if (i != ca && i != cb && i != cc) {
            mk[ii] = wmask[i]; P.srow[ii] = (u16)wrow[i];
            P.widx[ii] = (u16)(wbase + i); ++ii;
          }
        if (d == 7 && pg == 1)
          for (int i = 0; i < 4; ++i) mk2last[i] = mk[i];

        // incremental GF(2) independence: red[b] has leading bit b
        unsigned red[14] = {0};
        auto tryAdd = [&](unsigned x) -> bool {
          while (x) {
            int h = 31 - __builtin_clz(x);
            if (!red[h]) { red[h] = x; return true; }
            x ^= red[h];
          }
          return false;
        };
        for (int i = 0; i < 7; ++i) tryAdd((unsigned)wmask[i]);

        // low-nibble span tracker over the three cross masks
        unsigned reach = 1;
        auto addLow = [&](unsigned v) {
          unsigned nr = reach;
          for (int q = 0; q < 16; ++q)
            if ((reach >> q) & 1) nr |= 1u << (q ^ (v & 15u));
          reach = nr;
        };
        addLow(P.cm[0]); addLow(P.cm[1]); addLow(P.cm[2]);

        // scol[0] (t bit 2): low nibble completes the GF(2)^4 basis
        {
          unsigned v = 1;
          while (v < 16 && ((reach >> v) & 1)) ++v;
          if (v >= 16) v = 0;
          bool ok = false;
          for (unsigned h = 0; h < 1024u && !ok; ++h) {
            unsigned cand = v ^ (h << 4);
            if (cand && tryAdd(cand)) { P.scol[0] = (u16)cand; ok = true; }
          }
          for (unsigned cand = 1; cand < 16384u && !ok; ++cand)
            if (tryAdd(cand)) { P.scol[0] = (u16)cand; ok = true; }
        }
        // scol[1..6] (t bits 4..9): low nibble 0 preferred
        for (int i = 1; i < 7; ++i) {
          bool ok = false;
          for (unsigned h = 1; h < 1024u && !ok; ++h)
            if (tryAdd(h << 4)) { P.scol[i] = (u16)(h << 4); ok = true; }
          for (unsigned cand = 1; cand < 16384u && !ok; ++cand)
            if (tryAdd(cand)) { P.scol[i] = (u16)cand; ok = true; }
        }

        for (int e = 0; e < 16; ++e) {
          unsigned v = 0;
          for (int i = 0; i < 4; ++i)
            if ((e >> i) & 1) v ^= (unsigned)mk[i];
          P.xm[e] = (u16)v;
        }
      }
    } else {
      for (int w = 0; w < NQ; ++w) {
        const int bit = 13 - w;
        unsigned r = 0;
        for (int j = 0; j < NQ; ++j) r |= ((unsigned)(Lc[j] >> bit) & 1u) << j;
        C.zrow[w] = (u16)r;
        unsigned zf = 0;
        for (int i = 0; i < 4; ++i)
          zf |= (unsigned)(__builtin_popcount(r & (unsigned)mk2last[i]) & 1) << i;
        C.zfreq[w] = (u16)zf;
      }
    }
  }

  // workspace: [0,896) theta trig (float2); [1024, ...) albe (float4)
  const size_t needT = (size_t)(DEPTH * NQ) * sizeof(float2);
  const size_t needA = 1024 + (size_t)batch * NQ * sizeof(float4);
  const bool useT = ws_size >= 1024 && needT <= 1024;
  const bool useA = useT && ws_size >= needA;
  float2* tt = (float2*)d_ws;
  float4* albe = (float4*)((char*)d_ws + 1024);

  if (useT) {
    const int nAlbe = useA ? batch * NQ : 0;
    const int nwork = useA ? nAlbe : DEPTH * NQ;
    prep_kernel<<<(nwork + 255) / 256, 256, 0, stream>>>(
        inp, theta, tt, useA ? albe : nullptr, nAlbe);
    qsim_kernel<true><<<batch, TPB, 0, stream>>>(inp, theta, out, tt, albe,
                                                 useA ? 1 : 0, C);
  } else {
    qsim_kernel<false><<<batch, TPB, 0, stream>>>(inp, theta, out, nullptr,
                                                  nullptr, 0, C);
  }
}

// Round 9
// 242.639 us; speedup vs baseline: 1.0537x; 1.0537x over previous
//
#include <hip/hip_runtime.h>

typedef unsigned short u16;
typedef float f2 __attribute__((ext_vector_type(2)));

#define NQ 14
#define NSTATE (1 << NQ)   // 16384
#define DEPTH 8
#define TPB 1024

// ---------- host-side constants passed by value ----------
struct PassK {
  u16 cm[3];       // cross masks: lane^1, lane^2, lane^8
  u16 srow[7];     // sign rows of L: slots 0..3 in-reg, 4..6 cross
  u16 scol[7];     // complement basis: t bit 2 -> scol[0]; t bits 4..9 -> scol[1..6]
  u16 widx[7];     // within-layer theta index per slot (0..13)
  u16 xm[16];      // XOR combos of the 4 in-register pair masks
};

struct SimConsts {
  PassK pass[7][2];   // layers 1..7 x two 7-wire passes
  u16 zrow[14];       // rows of L_8 for <Z_w> sign
  u16 zfreq[14];      // 4-bit WHT frequency per wire (layer-7 pass-2 mask basis)
};

// ---------- device ----------
__device__ __forceinline__ f2 cmulv(f2 a, f2 b) {
  f2 r;
  r.x = a.x * b.x - a.y * b.y;
  r.y = a.x * b.y + a.y * b.x;
  return r;
}

template <int CTRL>
__device__ __forceinline__ f2 dpp_f2(f2 v) {
  f2 r;
  r.x = __int_as_float(
      __builtin_amdgcn_mov_dpp(__float_as_int(v.x), CTRL, 0xf, 0xf, true));
  r.y = __int_as_float(
      __builtin_amdgcn_mov_dpp(__float_as_int(v.y), CTRL, 0xf, 0xf, true));
  return r;
}

// 7-wire RY pass in TANGENT form (cosines deferred to a global scale):
// butterfly x' = x - t*y, y' = y + t*x; cross a' = a + tg*p.
// 4 wires in-register + 3 via DPP (lane^1, lane^2, lane^8).
template <bool USE_WS, bool WRITE>
__device__ __forceinline__ void ry7x(f2* st, const PassK& P, const float* th,
                                     const float2* tqd, int t,
                                     f2* a, unsigned* repx_out) {
  unsigned rep = ((t >> 2) & 1u) ? (unsigned)P.scol[0] : 0u;
  #pragma unroll
  for (int b = 1; b < 7; ++b)
    rep ^= ((t >> (3 + b)) & 1u) ? (unsigned)P.scol[b] : 0u;   // t bits 4..9
  unsigned repx = rep ^ ((t & 1) ? (unsigned)P.cm[0] : 0u)
                      ^ ((t & 2) ? (unsigned)P.cm[1] : 0u)
                      ^ ((t & 8) ? (unsigned)P.cm[2] : 0u);
  *repx_out = repx;

  float tv[7];
  #pragma unroll
  for (int i = 0; i < 7; ++i) {
    if constexpr (USE_WS) {
      tv[i] = tqd[P.widx[i]].x;        // uniform -> s_load (tan(theta/2))
    } else {
      float ss, cc; __sincosf(0.5f * th[P.widx[i]], &ss, &cc);
      float ca = (fabsf(cc) < 1e-20f) ? copysignf(1e-20f, cc) : cc;
      tv[i] = ss / ca;
    }
  }
  float ta[4];
  #pragma unroll
  for (int i = 0; i < 4; ++i)
    ta[i] = (__popc((unsigned)P.srow[i] & rep) & 1) ? -tv[i] : tv[i];
  const float tg4 =
      ((__popc((unsigned)P.srow[4] & rep) ^ t) & 1) ? tv[4] : -tv[4];
  const float tg5 =
      ((__popc((unsigned)P.srow[5] & rep) ^ (t >> 1)) & 1) ? tv[5] : -tv[5];
  const float tg6 =
      ((__popc((unsigned)P.srow[6] & rep) ^ (t >> 3)) & 1) ? tv[6] : -tv[6];

  const unsigned base = repx << 3;
  unsigned ad[16];
  #pragma unroll
  for (int e = 0; e < 16; ++e)
    ad[e] = base ^ (((unsigned)P.xm[e]) << 3);   // xm<<3 uniform (SGPR)

  #pragma unroll
  for (int e = 0; e < 16; ++e) a[e] = *(const f2*)((const char*)st + ad[e]);

  // cross slot 4: partner = lane^1 (quad_perm [1,0,3,2])
  #pragma unroll
  for (int e = 0; e < 16; ++e) {
    f2 p = dpp_f2<0xB1>(a[e]);
    a[e] = a[e] + tg4 * p;
  }
  // 4 in-register wires
  #pragma unroll
  for (int i = 0; i < 4; ++i) {
    const float ti = ta[i];
    #pragma unroll
    for (int e = 0; e < 16; ++e) {
      if (!(e & (1 << i))) {
        f2 xe = a[e], ye = a[e | (1 << i)];
        a[e]            = xe - ti * ye;
        a[e | (1 << i)] = ye + ti * xe;
      }
    }
  }
  // cross slot 5: partner = lane^2 (quad_perm [2,3,0,1])
  #pragma unroll
  for (int e = 0; e < 16; ++e) {
    f2 p = dpp_f2<0x4E>(a[e]);
    a[e] = a[e] + tg5 * p;
  }
  // cross slot 6: partner = lane^8 (row_ror:8 on 16-lane rows == XOR 8)
  #pragma unroll
  for (int e = 0; e < 16; ++e) {
    f2 p = dpp_f2<0x128>(a[e]);
    a[e] = a[e] + tg6 * p;
  }

  if constexpr (WRITE) {
    #pragma unroll
    for (int e = 0; e < 16; ++e) *(f2*)((char*)st + ad[e]) = a[e];
  }
}

template <bool USE_WS>
__global__ __launch_bounds__(TPB, 1) void qsim_kernel(
    const float* __restrict__ inp, const float* __restrict__ theta,
    float* __restrict__ out, const float2* __restrict__ tt,
    const float2* __restrict__ tq, const float* __restrict__ s2p,
    const float4* __restrict__ albe, int use_albe, SimConsts C) {
  __shared__ f2 st[NSTATE];   // 128 KiB
  const int s = blockIdx.x;
  const int t = threadIdx.x;

  // ---- init: product state after RX(inp) then RY(theta layer 0) (full gates)
  f2 A[NQ], B[NQ];
  if constexpr (USE_WS) {
    if (use_albe) {
      #pragma unroll
      for (int w = 0; w < NQ; ++w) {
        float4 v = albe[s * NQ + w];       // uniform -> s_load_dwordx4
        A[w].x = v.x; A[w].y = v.y;
        B[w].x = v.z; B[w].y = v.w;
      }
    } else {
      #pragma unroll
      for (int w = 0; w < NQ; ++w) {
        float sx, cx; __sincosf(0.5f * inp[s * NQ + w], &sx, &cx);
        float2 tvv = tt[w];
        A[w].x = tvv.x * cx; A[w].y = tvv.y * sx;
        B[w].x = tvv.y * cx; B[w].y = -tvv.x * sx;
      }
    }
  } else {
    #pragma unroll
    for (int w = 0; w < NQ; ++w) {
      float sx, cx; __sincosf(0.5f * inp[s * NQ + w], &sx, &cx);
      float stt, ctt; __sincosf(0.5f * theta[w], &stt, &ctt);
      A[w].x = ctt * cx; A[w].y = stt * sx;
      B[w].x = stt * cx; B[w].y = -ctt * sx;
    }
  }

  f2 a[16];
  {
    f2 rhi; rhi.x = 1.f; rhi.y = 0.f;
    #pragma unroll
    for (int b = 0; b < 10; ++b) {         // p bit b <- t bit b, wire 13-b
      const int w = 13 - b;
      f2 f = ((t >> b) & 1) ? B[w] : A[w];
      rhi = cmulv(rhi, f);
    }
    a[0] = rhi;
    #pragma unroll
    for (int k = 0; k < 4; ++k) {          // e bit k <-> p bit 10+k <-> wire 3-k
      const int w = 3 - k;
      const int sz = 1 << k;
      #pragma unroll
      for (int j = 0; j < 8; ++j) {
        if (j < sz) {
          f2 v = a[j];
          a[j]      = cmulv(v, A[w]);
          a[j + sz] = cmulv(v, B[w]);
        }
      }
    }
    #pragma unroll
    for (int e = 0; e < 16; ++e) st[(e << 10) | t] = a[e];
  }
  __syncthreads();

  // ---- layers 1..7, two 7-wire tangent passes each
  unsigned repx;
  #pragma unroll 1
  for (int d = 1; d <= 6; ++d) {
    const float* th = theta + d * NQ;
    const float2* tqd = USE_WS ? (tq + d * NQ) : nullptr;
    ry7x<USE_WS, true>(st, C.pass[d - 1][0], th, tqd, t, a, &repx);
    __syncthreads();
    ry7x<USE_WS, true>(st, C.pass[d - 1][1], th, tqd, t, a, &repx);
    __syncthreads();
  }
  {
    const float* th = theta + 7 * NQ;
    const float2* tqd = USE_WS ? (tq + 7 * NQ) : nullptr;
    ry7x<USE_WS, true>(st, C.pass[6][0], th, tqd, t, a, &repx);
    __syncthreads();
    // last pass: keep results in registers, fuse measurement
    ry7x<USE_WS, false>(st, C.pass[6][1], th, tqd, t, a, &repx);
  }
  __syncthreads();   // all reads of the final pass done before st is reused

  // ---- measurement: per-thread |amp|^2, 4-bit WHT in mask basis
  float pv[16];
  #pragma unroll
  for (int e = 0; e < 16; ++e) pv[e] = a[e].x * a[e].x + a[e].y * a[e].y;
  #pragma unroll
  for (int s4 = 0; s4 < 4; ++s4) {
    const int step = 1 << s4;
    #pragma unroll
    for (int e = 0; e < 16; ++e) {
      if (!(e & step)) {
        float x = pv[e], y = pv[e | step];
        pv[e] = x + y; pv[e | step] = x - y;
      }
    }
  }
  float* stf = (float*)st;
  #pragma unroll
  for (int e = 0; e < 16; ++e) stf[(e << 10) | t] = pv[e];
  __syncthreads();

  float acc[NQ];
  #pragma unroll
  for (int w = 0; w < NQ; ++w) {
    const unsigned zf = (unsigned)C.zfreq[w];
    float v = stf[(zf << 10) | (unsigned)t];
    acc[w] = (__popc((unsigned)C.zrow[w] & repx) & 1) ? -v : v;
  }
  #pragma unroll
  for (int w = 0; w < NQ; ++w) {
    #pragma unroll
    for (int off = 32; off > 0; off >>= 1)
      acc[w] += __shfl_xor(acc[w], off, 64);
  }
  __syncthreads();
  const int lane = t & 63, wid = t >> 6;   // wid in 0..15
  if (lane == 0) {
    #pragma unroll
    for (int w = 0; w < NQ; ++w) stf[wid * NQ + w] = acc[w];
  }
  __syncthreads();
  if (t < NQ) {
    float tot = 0.f;
    #pragma unroll
    for (int k = 0; k < 16; ++k) tot += stf[k * NQ + t];
    float s2v;
    if constexpr (USE_WS) {
      s2v = *s2p;
    } else {
      double pr = 1.0;
      for (int j = NQ; j < DEPTH * NQ; ++j) {
        float ss, cc; sincosf(0.5f * theta[j], &ss, &cc);
        pr *= (double)cc * (double)cc;
      }
      s2v = (float)pr;
    }
    out[s * NQ + t] = tot * s2v;
  }
}

// ---------- prep: precise trig tables + deferred-scale into workspace ----------
// ws float layout: [0,224) tt (c,s) pairs; [256,480) tq (t,c) pairs; [512] S^2
__global__ void prep_kernel(const float* __restrict__ inp,
                            const float* __restrict__ theta,
                            float* __restrict__ ws, float4* __restrict__ albe,
                            int nAlbe) {
  const int i = blockIdx.x * 256 + threadIdx.x;
  float2* tt = (float2*)ws;
  float2* tq = (float2*)(ws + 256);
  if (i < DEPTH * NQ) {
    float ss, cc; sincosf(0.5f * theta[i], &ss, &cc);
    tt[i] = make_float2(cc, ss);
    float ca = (fabsf(cc) < 1e-20f) ? copysignf(1e-20f, cc) : cc;
    tq[i] = make_float2(ss / ca, ca);
  }
  if (i == 0) {
    double pr = 1.0;
    for (int j = NQ; j < DEPTH * NQ; ++j) {
      double cc = cos(0.5 * (double)theta[j]);
      pr *= cc * cc;
    }
    ws[512] = (float)pr;
  }
  if (albe != nullptr && i < nAlbe) {
    const int w = i % NQ;
    float sx, cx; sincosf(0.5f * inp[i], &sx, &cx);
    float stt, ctt; sincosf(0.5f * theta[w], &stt, &ctt);
    albe[i] = make_float4(ctt * cx, stt * sx, stt * cx, -ctt * sx);
  }
}

// ---------- host: GF(2) linear algebra for the CNOT-ring permutation ----------
static inline unsigned ffwd(unsigned x) {
  unsigned t = x;
  t ^= t >> 1; t ^= t >> 2; t ^= t >> 4; t ^= t >> 8;
  unsigned y = t & 0x1FFFu;
  y |= (((t >> 13) ^ t) & 1u) << 13;
  return y;
}
static inline unsigned finv(unsigned y) {
  unsigned x = 0;
  for (int j = 0; j <= 11; ++j) x |= (((y >> j) ^ (y >> (j + 1))) & 1u) << j;
  x |= (((y >> 12) ^ (y >> 13) ^ y) & 1u) << 12;
  x |= (((y >> 13) ^ y) & 1u) << 13;
  return x;
}
static inline int rank4(unsigned a, unsigned b, unsigned c) {
  unsigned bas[4] = {0, 0, 0, 0};
  unsigned vv[3] = {a & 15u, b & 15u, c & 15u};
  int r = 0;
  for (int i = 0; i < 3; ++i) {
    unsigned u = vv[i];
    for (int bit = 3; bit >= 0; --bit)
      if (((u >> bit) & 1u) && bas[bit]) u ^= bas[bit];
    if (u) { bas[31 - __builtin_clz(u)] = u; ++r; }
  }
  return r;
}

extern "C" void kernel_launch(void* const* d_in, const int* in_sizes, int n_in,
                              void* d_out, int out_size, void* d_ws, size_t ws_size,
                              hipStream_t stream) {
  const float* inp = (const float*)d_in[0];
  const float* theta = (const float*)d_in[1];
  float* out = (float*)d_out;
  const int batch = in_sizes[0] / NQ;

  SimConsts C;
  u16 Lc[NQ], Kc[NQ];   // columns of L = F^d and K = L^-1
  u16 mk2last[4] = {0, 0, 0, 0};   // in-reg masks of layer-7 pass-2
  for (int j = 0; j < NQ; ++j) { Lc[j] = (u16)(1u << j); Kc[j] = (u16)(1u << j); }
  for (int d = 1; d <= 8; ++d) {
    u16 nL[NQ], nK[NQ];
    for (int j = 0; j < NQ; ++j) nL[j] = (u16)ffwd((unsigned)Lc[j]);
    for (int j = 0; j < NQ; ++j) {
      unsigned fj = finv(1u << j);
      unsigned v = 0;
      for (int b = 0; b < NQ; ++b) if ((fj >> b) & 1u) v ^= Kc[b];
      nK[j] = (u16)v;
    }
    for (int j = 0; j < NQ; ++j) { Lc[j] = nL[j]; Kc[j] = nK[j]; }

    if (d <= 7) {
      for (int pg = 0; pg < 2; ++pg) {
        const int wbase = pg * 7;
        PassK& P = C.pass[d - 1][pg];

        // wire masks (K columns) and sign rows (L rows)
        u16 wmask[7]; unsigned wrow[7];
        for (int i = 0; i < 7; ++i) {
          const int bit = 13 - (wbase + i);
          wmask[i] = Kc[bit];
          unsigned r = 0;
          for (int j = 0; j < NQ; ++j) r |= ((unsigned)(Lc[j] >> bit) & 1u) << j;
          wrow[i] = r;
        }

        // pick cross triple maximizing low-nibble GF(2) rank
        int ca = 0, cb = 1, cc = 2, bestRank = -1;
        for (int x = 0; x < 7; ++x)
          for (int y = x + 1; y < 7; ++y)
            for (int z = y + 1; z < 7; ++z) {
              int r = rank4(wmask[x], wmask[y], wmask[z]);
              if (r > bestRank) { bestRank = r; ca = x; cb = y; cc = z; }
            }
        P.cm[0] = wmask[ca]; P.cm[1] = wmask[cb]; P.cm[2] = wmask[cc];
        P.srow[4] = (u16)wrow[ca]; P.srow[5] = (u16)wrow[cb]; P.srow[6] = (u16)wrow[cc];
        P.widx[4] = (u16)(wbase + ca); P.widx[5] = (u16)(wbase + cb);
        P.widx[6] = (u16)(wbase + cc);
        u16 mk[4]; int ii = 0;
        for (int i = 0; i < 7; ++i)
          if (i != ca && i != cb && i != cc) {
            mk[ii] = wmask[i]; P.srow[ii] = (u16)wrow[i];
            P.widx[ii] = (u16)(wbase + i); ++ii;
          }
        if (d == 7 && pg == 1)
          for (int i = 0; i < 4; ++i) mk2last[i] = mk[i];

        // incremental GF(2) independence: red[b] has leading bit b
        unsigned red[14] = {0};
        auto tryAdd = [&](unsigned x) -> bool {
          while (x) {
            int h = 31 - __builtin_clz(x);
            if (!red[h]) { red[h] = x; return true; }
            x ^= red[h];
          }
          return false;
        };
        for (int i = 0; i < 7; ++i) tryAdd((unsigned)wmask[i]);

        // low-nibble GF(2)^4 basis from the cross masks
        unsigned lowb[4] = {0, 0, 0, 0};
        auto lowAdd = [&](unsigned x) -> bool {
          unsigned u = x & 15u;
          for (int b = 3; b >= 0; --b)
            if (((u >> b) & 1u) && lowb[b]) u ^= lowb[b];
          if (!u) return false;
          lowb[31 - __builtin_clz(u)] = u;
          return true;
        };
        lowAdd(P.cm[0]); lowAdd(P.cm[1]); lowAdd(P.cm[2]);

        // scol[0] (t bit 2) and scol[1] (t bit 4): complete the low-nibble basis
        for (int slot = 0; slot < 2; ++slot) {
          unsigned v = 0;
          for (unsigned cand = 1; cand < 16; ++cand) {
            unsigned u = cand;
            for (int b = 3; b >= 0; --b)
              if (((u >> b) & 1u) && lowb[b]) u ^= lowb[b];
            if (u) { v = cand; break; }
          }
          bool ok = false;
          for (unsigned h = 0; h < 1024u && !ok; ++h) {
            unsigned cand = v | (h << 4);
            if (cand && tryAdd(cand)) {
              P.scol[slot] = (u16)cand; lowAdd(cand); ok = true;
            }
          }
          for (unsigned cand = 1; cand < 16384u && !ok; ++cand)
            if (tryAdd(cand)) { P.scol[slot] = (u16)cand; lowAdd(cand); ok = true; }
        }
        // scol[2..6] (t bits 5..9): low nibble 0 preferred (uniform 2:1, free)
        for (int i = 2; i < 7; ++i) {
          bool ok = false;
          for (unsigned h = 1; h < 1024u && !ok; ++h)
            if (tryAdd(h << 4)) { P.scol[i] = (u16)(h << 4); ok = true; }
          for (unsigned cand = 1; cand < 16384u && !ok; ++cand)
            if (tryAdd(cand)) { P.scol[i] = (u16)cand; ok = true; }
        }

        for (int e = 0; e < 16; ++e) {
          unsigned v = 0;
          for (int i = 0; i < 4; ++i)
            if ((e >> i) & 1) v ^= (unsigned)mk[i];
          P.xm[e] = (u16)v;
        }
      }
    } else {
      for (int w = 0; w < NQ; ++w) {
        const int bit = 13 - w;
        unsigned r = 0;
        for (int j = 0; j < NQ; ++j) r |= ((unsigned)(Lc[j] >> bit) & 1u) << j;
        C.zrow[w] = (u16)r;
        unsigned zf = 0;
        for (int i = 0; i < 4; ++i)
          zf |= (unsigned)(__builtin_popcount(r & (unsigned)mk2last[i]) & 1) << i;
        C.zfreq[w] = (u16)zf;
      }
    }
  }

  // ws float layout: [0,224) tt; [256,480) tq; [512] S2; albe from byte 4096
  const size_t needT = 4096;
  const size_t needA = 4096 + (size_t)batch * NQ * sizeof(float4);
  const bool useT = ws_size >= needT;
  const bool useA = useT && ws_size >= needA;
  float* wsf = (float*)d_ws;
  float2* tt = (float2*)wsf;
  float2* tq = (float2*)(wsf + 256);
  float* s2p = wsf + 512;
  float4* albe = (float4*)((char*)d_ws + 4096);

  if (useT) {
    const int nAlbe = useA ? batch * NQ : 0;
    const int nwork = useA ? nAlbe : DEPTH * NQ;
    prep_kernel<<<(nwork + 255) / 256, 256, 0, stream>>>(
        inp, theta, wsf, useA ? albe : nullptr, nAlbe);
    qsim_kernel<true><<<batch, TPB, 0, stream>>>(inp, theta, out, tt, tq, s2p,
                                                 albe, useA ? 1 : 0, C);
  } else {
    qsim_kernel<false><<<batch, TPB, 0, stream>>>(inp, theta, out, nullptr,
                                                  nullptr, nullptr, nullptr, 0, C);
  }
}

// Round 10
// 205.308 us; speedup vs baseline: 1.2453x; 1.1818x over previous
//
#include <hip/hip_runtime.h>

typedef unsigned short u16;
typedef float f2 __attribute__((ext_vector_type(2)));

#define NQ 14
#define NSTATE (1 << NQ)   // 16384
#define DEPTH 8
#define TPB 1024

// ---------- host-side constants passed by value ----------
struct PassK {
  u16 pcol[10];    // PHYSICAL rep columns for t bits 0..9
  u16 sm[7];       // sign masks over t; slots 0..3 in-reg, 4..6 cross
  u16 widx[7];     // within-layer theta index per slot (0..13)
  u16 pxm[16];     // PHYSICAL xm (XOR combos of in-reg masks, mapped by Phi)
};

struct SimConsts {
  PassK pass[14];  // layers 1..7 x two 7-wire passes
  u16 zm[14];      // measurement sign masks over t (last-pass basis)
  u16 zfreq[14];   // 4-bit WHT frequency per wire (last-pass mask basis)
  u16 de[16];      // init-write address delta per e (Phi correction)
  u16 dcolw[4];    // init-write delta columns for t bits 6..9
};

// ---------- device ----------
__device__ __forceinline__ f2 cmulv(f2 a, f2 b) {
  f2 r;
  r.x = a.x * b.x - a.y * b.y;
  r.y = a.x * b.y + a.y * b.x;
  return r;
}

template <int CTRL>
__device__ __forceinline__ f2 dpp_f2(f2 v) {
  f2 r;
  r.x = __int_as_float(
      __builtin_amdgcn_mov_dpp(__float_as_int(v.x), CTRL, 0xf, 0xf, true));
  r.y = __int_as_float(
      __builtin_amdgcn_mov_dpp(__float_as_int(v.y), CTRL, 0xf, 0xf, true));
  return r;
}

// 7-wire RY pass in TANGENT form; 4 wires in-register + 3 via DPP
// (lane^1, lane^2, lane^8). Addresses are PHYSICAL (Phi layout);
// signs come from precomputed 10-bit t-masks.
template <bool USE_WS, bool WRITE>
__device__ __forceinline__ void ry7x(f2* st, const PassK& P, const float* th,
                                     const float2* tqd, int t, f2* a) {
  unsigned rep = 0;
  #pragma unroll
  for (int b = 0; b < 10; ++b)
    rep ^= ((t >> b) & 1u) ? (unsigned)P.pcol[b] : 0u;

  float tv[7];
  #pragma unroll
  for (int i = 0; i < 7; ++i) {
    if constexpr (USE_WS) {
      tv[i] = tqd[P.widx[i]].x;        // uniform -> s_load (tan(theta/2))
    } else {
      float ss, cc; __sincosf(0.5f * th[P.widx[i]], &ss, &cc);
      float ca = (fabsf(cc) < 1e-20f) ? copysignf(1e-20f, cc) : cc;
      tv[i] = ss / ca;
    }
  }
  float tg[7];
  #pragma unroll
  for (int i = 0; i < 4; ++i)
    tg[i] = (__popc((unsigned)P.sm[i] & (unsigned)t) & 1) ? -tv[i] : tv[i];
  #pragma unroll
  for (int i = 4; i < 7; ++i)
    tg[i] = (__popc((unsigned)P.sm[i] & (unsigned)t) & 1) ? tv[i] : -tv[i];

  const unsigned base = rep << 3;
  unsigned ad[16];
  #pragma unroll
  for (int e = 0; e < 16; ++e)
    ad[e] = base ^ (((unsigned)P.pxm[e]) << 3);   // pxm<<3 uniform (SGPR)

  #pragma unroll
  for (int e = 0; e < 16; ++e) a[e] = *(const f2*)((const char*)st + ad[e]);

  // cross slot 4: partner = lane^1 (quad_perm [1,0,3,2])
  #pragma unroll
  for (int e = 0; e < 16; ++e) {
    f2 p = dpp_f2<0xB1>(a[e]);
    a[e] = a[e] + tg[4] * p;
  }
  // 4 in-register wires
  #pragma unroll
  for (int i = 0; i < 4; ++i) {
    const float ti = tg[i];
    #pragma unroll
    for (int e = 0; e < 16; ++e) {
      if (!(e & (1 << i))) {
        f2 xe = a[e], ye = a[e | (1 << i)];
        a[e]            = xe - ti * ye;
        a[e | (1 << i)] = ye + ti * xe;
      }
    }
  }
  // cross slot 5: partner = lane^2 (quad_perm [2,3,0,1])
  #pragma unroll
  for (int e = 0; e < 16; ++e) {
    f2 p = dpp_f2<0x4E>(a[e]);
    a[e] = a[e] + tg[5] * p;
  }
  // cross slot 6: partner = lane^8 (row_ror:8 on 16-lane rows == XOR 8)
  #pragma unroll
  for (int e = 0; e < 16; ++e) {
    f2 p = dpp_f2<0x128>(a[e]);
    a[e] = a[e] + tg[6] * p;
  }

  if constexpr (WRITE) {
    #pragma unroll
    for (int e = 0; e < 16; ++e) *(f2*)((char*)st + ad[e]) = a[e];
  }
}

template <bool USE_WS>
__global__ __launch_bounds__(TPB, 1) void qsim_kernel(
    const float* __restrict__ inp, const float* __restrict__ theta,
    float* __restrict__ out, const float2* __restrict__ tt,
    const float2* __restrict__ tq, const float* __restrict__ s2p,
    const float4* __restrict__ albe, int use_albe, SimConsts C) {
  __shared__ f2 st[NSTATE];   // 128 KiB
  const int s = blockIdx.x;
  const int t = threadIdx.x;

  // ---- init: product state after RX(inp) then RY(theta layer 0) (full gates)
  f2 A[NQ], B[NQ];
  if constexpr (USE_WS) {
    if (use_albe) {
      #pragma unroll
      for (int w = 0; w < NQ; ++w) {
        float4 v = albe[s * NQ + w];       // uniform -> s_load_dwordx4
        A[w].x = v.x; A[w].y = v.y;
        B[w].x = v.z; B[w].y = v.w;
      }
    } else {
      #pragma unroll
      for (int w = 0; w < NQ; ++w) {
        float sx, cx; __sincosf(0.5f * inp[s * NQ + w], &sx, &cx);
        float2 tvv = tt[w];
        A[w].x = tvv.x * cx; A[w].y = tvv.y * sx;
        B[w].x = tvv.y * cx; B[w].y = -tvv.x * sx;
      }
    }
  } else {
    #pragma unroll
    for (int w = 0; w < NQ; ++w) {
      float sx, cx; __sincosf(0.5f * inp[s * NQ + w], &sx, &cx);
      float stt, ctt; __sincosf(0.5f * theta[w], &stt, &ctt);
      A[w].x = ctt * cx; A[w].y = stt * sx;
      B[w].x = stt * cx; B[w].y = -ctt * sx;
    }
  }

  f2 a[16];
  {
    f2 rhi; rhi.x = 1.f; rhi.y = 0.f;
    #pragma unroll
    for (int b = 0; b < 10; ++b) {         // p bit b <- t bit b, wire 13-b
      const int w = 13 - b;
      f2 f = ((t >> b) & 1) ? B[w] : A[w];
      rhi = cmulv(rhi, f);
    }
    a[0] = rhi;
    #pragma unroll
    for (int k = 0; k < 4; ++k) {          // e bit k <-> p bit 10+k <-> wire 3-k
      const int w = 3 - k;
      const int sz = 1 << k;
      #pragma unroll
      for (int j = 0; j < 8; ++j) {
        if (j < sz) {
          f2 v = a[j];
          a[j]      = cmulv(v, A[w]);
          a[j + sz] = cmulv(v, B[w]);
        }
      }
    }
    // Phi-corrected physical store addresses
    unsigned dw = 0;
    #pragma unroll
    for (int j = 0; j < 4; ++j)
      dw ^= ((t >> (6 + j)) & 1u) ? (unsigned)C.dcolw[j] : 0u;
    #pragma unroll
    for (int e = 0; e < 16; ++e)
      st[(((unsigned)e << 10) | (unsigned)t) ^ (unsigned)C.de[e] ^ dw] = a[e];
  }
  __syncthreads();

  // ---- layers 1..7, two 7-wire tangent passes each
  #pragma unroll 1
  for (int d = 1; d <= 6; ++d) {
    const float* th = theta + d * NQ;
    const float2* tqd = USE_WS ? (tq + d * NQ) : nullptr;
    ry7x<USE_WS, true>(st, C.pass[(d - 1) * 2 + 0], th, tqd, t, a);
    __syncthreads();
    ry7x<USE_WS, true>(st, C.pass[(d - 1) * 2 + 1], th, tqd, t, a);
    __syncthreads();
  }
  {
    const float* th = theta + 7 * NQ;
    const float2* tqd = USE_WS ? (tq + 7 * NQ) : nullptr;
    ry7x<USE_WS, true>(st, C.pass[12], th, tqd, t, a);
    __syncthreads();
    // last pass: keep results in registers, fuse measurement
    ry7x<USE_WS, false>(st, C.pass[13], th, tqd, t, a);
  }
  __syncthreads();   // all reads of the final pass done before st is reused

  // ---- measurement: per-thread |amp|^2, 4-bit WHT in mask basis
  float pv[16];
  #pragma unroll
  for (int e = 0; e < 16; ++e) pv[e] = a[e].x * a[e].x + a[e].y * a[e].y;
  #pragma unroll
  for (int s4 = 0; s4 < 4; ++s4) {
    const int step = 1 << s4;
    #pragma unroll
    for (int e = 0; e < 16; ++e) {
      if (!(e & step)) {
        float x = pv[e], y = pv[e | step];
        pv[e] = x + y; pv[e | step] = x - y;
      }
    }
  }
  float* stf = (float*)st;
  #pragma unroll
  for (int e = 0; e < 16; ++e) stf[(e << 10) | t] = pv[e];
  __syncthreads();

  float acc[NQ];
  #pragma unroll
  for (int w = 0; w < NQ; ++w) {
    const unsigned zf = (unsigned)C.zfreq[w];
    float v = stf[(zf << 10) | (unsigned)t];
    acc[w] = (__popc((unsigned)C.zm[w] & (unsigned)t) & 1) ? -v : v;
  }
  #pragma unroll
  for (int w = 0; w < NQ; ++w) {
    #pragma unroll
    for (int off = 32; off > 0; off >>= 1)
      acc[w] += __shfl_xor(acc[w], off, 64);
  }
  __syncthreads();
  const int lane = t & 63, wid = t >> 6;   // wid in 0..15
  if (lane == 0) {
    #pragma unroll
    for (int w = 0; w < NQ; ++w) stf[wid * NQ + w] = acc[w];
  }
  __syncthreads();
  if (t < NQ) {
    float tot = 0.f;
    #pragma unroll
    for (int k = 0; k < 16; ++k) tot += stf[k * NQ + t];
    float s2v;
    if constexpr (USE_WS) {
      s2v = *s2p;
    } else {
      double pr = 1.0;
      for (int j = NQ; j < DEPTH * NQ; ++j) {
        float ss, cc; sincosf(0.5f * theta[j], &ss, &cc);
        pr *= (double)cc * (double)cc;
      }
      s2v = (float)pr;
    }
    out[s * NQ + t] = tot * s2v;
  }
}

// ---------- prep: precise trig tables + deferred-scale into workspace ----------
// ws float layout: [0,224) tt (c,s) pairs; [256,480) tq (t,c) pairs; [512] S^2
__global__ void prep_kernel(const float* __restrict__ inp,
                            const float* __restrict__ theta,
                            float* __restrict__ ws, float4* __restrict__ albe,
                            int nAlbe) {
  const int i = blockIdx.x * 256 + threadIdx.x;
  float2* tt = (float2*)ws;
  float2* tq = (float2*)(ws + 256);
  if (i < DEPTH * NQ) {
    float ss, cc; sincosf(0.5f * theta[i], &ss, &cc);
    tt[i] = make_float2(cc, ss);
    float ca = (fabsf(cc) < 1e-20f) ? copysignf(1e-20f, cc) : cc;
    tq[i] = make_float2(ss / ca, ca);
  }
  if (i == 0) {
    double pr = 1.0;
    for (int j = NQ; j < DEPTH * NQ; ++j) {
      double cc = cos(0.5 * (double)theta[j]);
      pr *= cc * cc;
    }
    ws[512] = (float)pr;
  }
  if (albe != nullptr && i < nAlbe) {
    const int w = i % NQ;
    float sx, cx; sincosf(0.5f * inp[i], &sx, &cx);
    float stt, ctt; sincosf(0.5f * theta[w], &stt, &ctt);
    albe[i] = make_float4(ctt * cx, stt * sx, stt * cx, -ctt * sx);
  }
}

// ---------- host: GF(2) linear algebra for the CNOT-ring permutation ----------
static inline unsigned ffwd(unsigned x) {
  unsigned t = x;
  t ^= t >> 1; t ^= t >> 2; t ^= t >> 4; t ^= t >> 8;
  unsigned y = t & 0x1FFFu;
  y |= (((t >> 13) ^ t) & 1u) << 13;
  return y;
}
static inline unsigned finv(unsigned y) {
  unsigned x = 0;
  for (int j = 0; j <= 11; ++j) x |= (((y >> j) ^ (y >> (j + 1))) & 1u) << j;
  x |= (((y >> 12) ^ (y >> 13) ^ y) & 1u) << 12;
  x |= (((y >> 13) ^ y) & 1u) << 13;
  return x;
}
static inline int rank3n(unsigned a, unsigned b, unsigned c) {
  unsigned bas[4] = {0, 0, 0, 0};
  unsigned vv[3] = {a & 15u, b & 15u, c & 15u};
  int r = 0;
  for (int i = 0; i < 3; ++i) {
    unsigned u = vv[i];
    for (int bit = 3; bit >= 0; --bit)
      if (((u >> bit) & 1u) && bas[bit]) u ^= bas[bit];
    if (u) { bas[31 - __builtin_clz(u)] = u; ++r; }
  }
  return r;
}
static inline unsigned phi_full(unsigned m, const unsigned* ac) {
  unsigned d = 0;
  for (int j = 0; j < 8; ++j)
    if ((m >> (6 + j)) & 1u) d ^= ac[j];
  return m ^ d;
}
static inline int par(unsigned x) { return __builtin_popcount(x) & 1; }

static int scoreA(const unsigned* ac, const u16 am[14][7], int bail) {
  int s = 0;
  for (int p = 0; p < 14; ++p) {
    unsigned pm[7];
    for (int i = 0; i < 7; ++i) pm[i] = phi_full((unsigned)am[p][i], ac) & 15u;
    int best = 0;
    for (int x = 0; x < 7 && best < 3; ++x)
      for (int y = x + 1; y < 7 && best < 3; ++y)
        for (int z = y + 1; z < 7 && best < 3; ++z) {
          int r = rank3n(pm[x], pm[y], pm[z]);
          if (r > best) best = r;
        }
    if (best < 3) s += 3 - best;
    if (s >= bail) return s;
  }
  return s;
}

extern "C" void kernel_launch(void* const* d_in, const int* in_sizes, int n_in,
                              void* d_out, int out_size, void* d_ws, size_t ws_size,
                              hipStream_t stream) {
  const float* inp = (const float*)d_in[0];
  const float* theta = (const float*)d_in[1];
  float* out = (float*)d_out;
  const int batch = in_sizes[0] / NQ;

  // ---- collect per-pass wire masks (K cols) and sign rows (L rows)
  u16 Lc[NQ], Kc[NQ];
  u16 allmask[14][7]; unsigned allrow[14][7];
  u16 zrow[NQ];
  for (int j = 0; j < NQ; ++j) { Lc[j] = (u16)(1u << j); Kc[j] = (u16)(1u << j); }
  for (int d = 1; d <= 8; ++d) {
    u16 nL[NQ], nK[NQ];
    for (int j = 0; j < NQ; ++j) nL[j] = (u16)ffwd((unsigned)Lc[j]);
    for (int j = 0; j < NQ; ++j) {
      unsigned fj = finv(1u << j);
      unsigned v = 0;
      for (int b = 0; b < NQ; ++b) if ((fj >> b) & 1u) v ^= Kc[b];
      nK[j] = (u16)v;
    }
    for (int j = 0; j < NQ; ++j) { Lc[j] = nL[j]; Kc[j] = nK[j]; }

    if (d <= 7) {
      for (int pg = 0; pg < 2; ++pg) {
        const int p = (d - 1) * 2 + pg;
        const int wbase = pg * 7;
        for (int i = 0; i < 7; ++i) {
          const int bit = 13 - (wbase + i);
          allmask[p][i] = Kc[bit];
          unsigned r = 0;
          for (int j = 0; j < NQ; ++j) r |= ((unsigned)(Lc[j] >> bit) & 1u) << j;
          allrow[p][i] = r;
        }
      }
    } else {
      for (int w = 0; w < NQ; ++w) {
        const int bit = 13 - w;
        unsigned r = 0;
        for (int j = 0; j < NQ; ++j) r |= ((unsigned)(Lc[j] >> bit) & 1u) << j;
        zrow[w] = (u16)r;
      }
    }
  }

  // ---- search layout map A (8 cols -> low4) so every pass has a rank-3 triple
  unsigned acol[8] = {0, 0, 0, 0, 0, 0, 0, 0};
  int bestSc = scoreA(acol, allmask, 1 << 30);
  if (bestSc > 0) {
    unsigned long long seed = 88172645463325252ULL;
    for (int it = 0; it < 20000 && bestSc > 0; ++it) {
      unsigned cand[8];
      for (int j = 0; j < 8; ++j) {
        seed ^= seed << 13; seed ^= seed >> 7; seed ^= seed << 17;
        cand[j] = (unsigned)(seed & 15u);
      }
      int sc = scoreA(cand, allmask, bestSc);
      if (sc < bestSc) {
        bestSc = sc;
        for (int j = 0; j < 8; ++j) acol[j] = cand[j];
      }
    }
  }

  // ---- build pass constants
  SimConsts C;
  u16 mkLast[4] = {0, 0, 0, 0};
  unsigned lcolLast[10] = {0};
  for (int p = 0; p < 14; ++p) {
    PassK& P = C.pass[p];
    const int pg = p & 1, wbase = pg * 7;

    unsigned pm[7];
    for (int i = 0; i < 7; ++i) pm[i] = phi_full((unsigned)allmask[p][i], acol) & 15u;
    int ca = 0, cb = 1, cc2 = 2, best = -1;
    for (int x = 0; x < 7; ++x)
      for (int y = x + 1; y < 7; ++y)
        for (int z = y + 1; z < 7; ++z) {
          int r = rank3n(pm[x], pm[y], pm[z]);
          if (r > best) { best = r; ca = x; cb = y; cc2 = z; }
        }

    unsigned cmL[3] = {allmask[p][ca], allmask[p][cb], allmask[p][cc2]};
    unsigned srowAll[7];
    srowAll[4] = allrow[p][ca]; srowAll[5] = allrow[p][cb]; srowAll[6] = allrow[p][cc2];
    P.widx[4] = (u16)(wbase + ca); P.widx[5] = (u16)(wbase + cb);
    P.widx[6] = (u16)(wbase + cc2);
    u16 mk[4]; int ii = 0;
    for (int i = 0; i < 7; ++i)
      if (i != ca && i != cb && i != cc2) {
        mk[ii] = allmask[p][i]; srowAll[ii] = allrow[p][i];
        P.widx[ii] = (u16)(wbase + i); ++ii;
      }
    if (p == 13) for (int i = 0; i < 4; ++i) mkLast[i] = mk[i];

    // full-rank (14-dim) independence tracker
    unsigned red[14] = {0};
    auto tryAdd = [&](unsigned x) -> bool {
      while (x) {
        int h = 31 - __builtin_clz(x);
        if (!red[h]) { red[h] = x; return true; }
        x ^= red[h];
      }
      return false;
    };
    for (int i = 0; i < 7; ++i) tryAdd((unsigned)allmask[p][i]);

    // physical low4 span of the cross triple
    unsigned nb[4] = {0, 0, 0, 0};
    for (int i = 0; i < 3; ++i) {
      unsigned u = pm[i == 0 ? ca : (i == 1 ? cb : cc2)];
      for (int bit = 3; bit >= 0; --bit)
        if (((u >> bit) & 1u) && nb[bit]) u ^= nb[bit];
      if (u) nb[31 - __builtin_clz(u)] = u;
    }
    // target low4 for scol0: smallest value outside the span
    unsigned uTarget = 0;
    for (unsigned v = 1; v < 16; ++v) {
      unsigned r = v;
      for (int bit = 3; bit >= 0; --bit)
        if (((r >> bit) & 1u) && nb[bit]) r ^= nb[bit];
      if (r) { uTarget = v; break; }
    }
    unsigned scol[7];
    {
      bool ok = false;
      for (unsigned h = 0; h < 256u && !ok; ++h) {
        unsigned d4 = 0;
        for (int j = 0; j < 8; ++j) if ((h >> j) & 1u) d4 ^= acol[j];
        unsigned v = ((uTarget ^ d4) & 15u) | (h << 6);
        if (v && tryAdd(v)) { scol[0] = v; ok = true; }
      }
      for (unsigned cand = 1; cand < 16384u && !ok; ++cand)
        if (tryAdd(cand)) { scol[0] = cand; ok = true; }
    }
    for (int i2 = 1; i2 < 7; ++i2) {
      bool ok = false;
      for (unsigned h = 1; h < 256u && !ok; ++h)
        if (tryAdd(h << 6)) { scol[i2] = h << 6; ok = true; }
      for (unsigned cand = 1; cand < 16384u && !ok; ++cand)
        if (tryAdd(cand)) { scol[i2] = cand; ok = true; }
    }

    unsigned lcol[10] = {cmL[0], cmL[1], scol[0], cmL[2],
                         scol[1], scol[2], scol[3], scol[4], scol[5], scol[6]};
    for (int b = 0; b < 10; ++b) P.pcol[b] = (u16)phi_full(lcol[b], acol);
    if (p == 13) for (int b = 0; b < 10; ++b) lcolLast[b] = lcol[b];

    for (int i = 0; i < 7; ++i) {
      unsigned m = 0;
      for (int b = 0; b < 10; ++b)
        m |= (unsigned)par(srowAll[i] & lcol[b]) << b;
      P.sm[i] = (u16)m;
    }
    for (int e = 0; e < 16; ++e) {
      unsigned v = 0;
      for (int i = 0; i < 4; ++i)
        if ((e >> i) & 1) v ^= (unsigned)mk[i];
      P.pxm[e] = (u16)phi_full(v, acol);
    }
  }

  // measurement constants (last-pass basis)
  for (int w = 0; w < NQ; ++w) {
    unsigned zf = 0;
    for (int i = 0; i < 4; ++i)
      zf |= (unsigned)par((unsigned)zrow[w] & (unsigned)mkLast[i]) << i;
    C.zfreq[w] = (u16)zf;
    unsigned m = 0;
    for (int b = 0; b < 10; ++b)
      m |= (unsigned)par((unsigned)zrow[w] & lcolLast[b]) << b;
    C.zm[w] = (u16)m;
  }
  // init-write Phi deltas
  for (int e = 0; e < 16; ++e) {
    unsigned d4 = 0;
    for (int k = 0; k < 4; ++k)
      if ((e >> k) & 1) d4 ^= acol[4 + k];
    C.de[e] = (u16)d4;
  }
  for (int j = 0; j < 4; ++j) C.dcolw[j] = (u16)acol[j];

  // ws float layout: [0,224) tt; [256,480) tq; [512] S2; albe from byte 4096
  const size_t needT = 4096;
  const size_t needA = 4096 + (size_t)batch * NQ * sizeof(float4);
  const bool useT = ws_size >= needT;
  const bool useA = useT && ws_size >= needA;
  float* wsf = (float*)d_ws;
  float2* tt = (float2*)wsf;
  float2* tq = (float2*)(wsf + 256);
  float* s2p = wsf + 512;
  float4* albe = (float4*)((char*)d_ws + 4096);

  if (useT) {
    const int nAlbe = useA ? batch * NQ : 0;
    const int nwork = useA ? nAlbe : DEPTH * NQ;
    prep_kernel<<<(nwork + 255) / 256, 256, 0, stream>>>(
        inp, theta, wsf, useA ? albe : nullptr, nAlbe);
    qsim_kernel<true><<<batch, TPB, 0, stream>>>(inp, theta, out, tt, tq, s2p,
                                                 albe, useA ? 1 : 0, C);
  } else {
    qsim_kernel<false><<<batch, TPB, 0, stream>>>(inp, theta, out, nullptr,
                                                  nullptr, nullptr, nullptr, 0, C);
  }
}

// Round 11
// 188.783 us; speedup vs baseline: 1.3543x; 1.0875x over previous
//
#include <hip/hip_runtime.h>

typedef unsigned short u16;
typedef float f2 __attribute__((ext_vector_type(2)));

#define NQ 14
#define NSTATE (1 << NQ)   // 16384
#define DEPTH 8
#define TPB 1024

// ---------- host-side constants passed by value ----------
struct PassK {
  u16 pcol[10];    // PHYSICAL rep columns for t bits 0..9
  u16 sm[7];       // sign masks over t; slots 0..3 in-reg, 4..6 cross
  u16 widx[7];     // within-layer theta index per slot (0..13)
  u16 pxm[16];     // PHYSICAL xm (XOR combos of in-reg masks, mapped by Phi)
};

struct SimConsts {
  PassK pass[14];  // layers 1..7 x two 7-wire passes
  u16 zm[14];      // measurement sign masks over t (last-pass basis)
  u16 zfreq[14];   // 4-bit WHT frequency per wire (last-pass mask basis)
  u16 de[16];      // init-write address delta per e (Phi correction)
  u16 dcolw[4];    // init-write delta columns for t bits 6..9
};

// ---------- device ----------
__device__ __forceinline__ f2 cmulv(f2 a, f2 b) {
  f2 r;
  r.x = a.x * b.x - a.y * b.y;
  r.y = a.x * b.y + a.y * b.x;
  return r;
}

// Fused cross-wire butterfly: a += tg * partner(a), partner via DPP on src0.
// Single v_fmac_f32_dpp per component reads the partner lane's OLD value and
// accumulates in place (all lanes read before any write within one instr).
// s_nop 1 covers the 2-wait-state VALU-write -> DPP-read hazard.
__device__ __forceinline__ void xfmac_l1(f2& v, float tg) {   // partner lane^1
  float x = v.x, y = v.y;
  asm volatile(
      "s_nop 1\n\t"
      "v_fmac_f32_dpp %0, %0, %2 quad_perm:[1,0,3,2] row_mask:0xf bank_mask:0xf\n\t"
      "v_fmac_f32_dpp %1, %1, %2 quad_perm:[1,0,3,2] row_mask:0xf bank_mask:0xf"
      : "+v"(x), "+v"(y) : "v"(tg));
  v.x = x; v.y = y;
}
__device__ __forceinline__ void xfmac_l2(f2& v, float tg) {   // partner lane^2
  float x = v.x, y = v.y;
  asm volatile(
      "s_nop 1\n\t"
      "v_fmac_f32_dpp %0, %0, %2 quad_perm:[2,3,0,1] row_mask:0xf bank_mask:0xf\n\t"
      "v_fmac_f32_dpp %1, %1, %2 quad_perm:[2,3,0,1] row_mask:0xf bank_mask:0xf"
      : "+v"(x), "+v"(y) : "v"(tg));
  v.x = x; v.y = y;
}
__device__ __forceinline__ void xfmac_l8(f2& v, float tg) {   // partner lane^8
  float x = v.x, y = v.y;
  asm volatile(
      "s_nop 1\n\t"
      "v_fmac_f32_dpp %0, %0, %2 row_ror:8 row_mask:0xf bank_mask:0xf\n\t"
      "v_fmac_f32_dpp %1, %1, %2 row_ror:8 row_mask:0xf bank_mask:0xf"
      : "+v"(x), "+v"(y) : "v"(tg));
  v.x = x; v.y = y;
}

// 7-wire RY pass in TANGENT form; 4 wires in-register + 3 via fused DPP-fmac
// (lane^1, lane^2, lane^8). Addresses are PHYSICAL (Phi layout);
// signs come from precomputed 10-bit t-masks.
template <bool USE_WS, bool WRITE>
__device__ __forceinline__ void ry7x(f2* st, const PassK& P, const float* th,
                                     const float2* tqd, int t, f2* a) {
  unsigned rep = 0;
  #pragma unroll
  for (int b = 0; b < 10; ++b)
    rep ^= ((t >> b) & 1u) ? (unsigned)P.pcol[b] : 0u;

  float tv[7];
  #pragma unroll
  for (int i = 0; i < 7; ++i) {
    if constexpr (USE_WS) {
      tv[i] = tqd[P.widx[i]].x;        // uniform -> s_load (tan(theta/2))
    } else {
      float ss, cc; __sincosf(0.5f * th[P.widx[i]], &ss, &cc);
      float ca = (fabsf(cc) < 1e-20f) ? copysignf(1e-20f, cc) : cc;
      tv[i] = ss / ca;
    }
  }
  float tg[7];
  #pragma unroll
  for (int i = 0; i < 4; ++i)
    tg[i] = (__popc((unsigned)P.sm[i] & (unsigned)t) & 1) ? -tv[i] : tv[i];
  #pragma unroll
  for (int i = 4; i < 7; ++i)
    tg[i] = (__popc((unsigned)P.sm[i] & (unsigned)t) & 1) ? tv[i] : -tv[i];

  const unsigned base = rep << 3;
  unsigned ad[16];
  #pragma unroll
  for (int e = 0; e < 16; ++e)
    ad[e] = base ^ (((unsigned)P.pxm[e]) << 3);   // pxm<<3 uniform (SGPR)

  #pragma unroll
  for (int e = 0; e < 16; ++e) a[e] = *(const f2*)((const char*)st + ad[e]);

  // cross slot 4: partner = lane^1
  #pragma unroll
  for (int e = 0; e < 16; ++e) xfmac_l1(a[e], tg[4]);
  // 4 in-register wires
  #pragma unroll
  for (int i = 0; i < 4; ++i) {
    const float ti = tg[i];
    #pragma unroll
    for (int e = 0; e < 16; ++e) {
      if (!(e & (1 << i))) {
        f2 xe = a[e], ye = a[e | (1 << i)];
        a[e]            = xe - ti * ye;
        a[e | (1 << i)] = ye + ti * xe;
      }
    }
  }
  // cross slot 5: partner = lane^2
  #pragma unroll
  for (int e = 0; e < 16; ++e) xfmac_l2(a[e], tg[5]);
  // cross slot 6: partner = lane^8
  #pragma unroll
  for (int e = 0; e < 16; ++e) xfmac_l8(a[e], tg[6]);

  if constexpr (WRITE) {
    #pragma unroll
    for (int e = 0; e < 16; ++e) *(f2*)((char*)st + ad[e]) = a[e];
  }
}

template <bool USE_WS>
__global__ __launch_bounds__(TPB, 1) void qsim_kernel(
    const float* __restrict__ inp, const float* __restrict__ theta,
    float* __restrict__ out, const float2* __restrict__ tt,
    const float2* __restrict__ tq, const float* __restrict__ s2p,
    const float4* __restrict__ albe, int use_albe, SimConsts C) {
  __shared__ f2 st[NSTATE];   // 128 KiB
  const int s = blockIdx.x;
  const int t = threadIdx.x;

  // ---- init: product state after RX(inp) then RY(theta layer 0) (full gates)
  f2 A[NQ], B[NQ];
  if constexpr (USE_WS) {
    if (use_albe) {
      #pragma unroll
      for (int w = 0; w < NQ; ++w) {
        float4 v = albe[s * NQ + w];       // uniform -> s_load_dwordx4
        A[w].x = v.x; A[w].y = v.y;
        B[w].x = v.z; B[w].y = v.w;
      }
    } else {
      #pragma unroll
      for (int w = 0; w < NQ; ++w) {
        float sx, cx; __sincosf(0.5f * inp[s * NQ + w], &sx, &cx);
        float2 tvv = tt[w];
        A[w].x = tvv.x * cx; A[w].y = tvv.y * sx;
        B[w].x = tvv.y * cx; B[w].y = -tvv.x * sx;
      }
    }
  } else {
    #pragma unroll
    for (int w = 0; w < NQ; ++w) {
      float sx, cx; __sincosf(0.5f * inp[s * NQ + w], &sx, &cx);
      float stt, ctt; __sincosf(0.5f * theta[w], &stt, &ctt);
      A[w].x = ctt * cx; A[w].y = stt * sx;
      B[w].x = stt * cx; B[w].y = -ctt * sx;
    }
  }

  f2 a[16];
  {
    f2 rhi; rhi.x = 1.f; rhi.y = 0.f;
    #pragma unroll
    for (int b = 0; b < 10; ++b) {         // p bit b <- t bit b, wire 13-b
      const int w = 13 - b;
      f2 f = ((t >> b) & 1) ? B[w] : A[w];
      rhi = cmulv(rhi, f);
    }
    a[0] = rhi;
    #pragma unroll
    for (int k = 0; k < 4; ++k) {          // e bit k <-> p bit 10+k <-> wire 3-k
      const int w = 3 - k;
      const int sz = 1 << k;
      #pragma unroll
      for (int j = 0; j < 8; ++j) {
        if (j < sz) {
          f2 v = a[j];
          a[j]      = cmulv(v, A[w]);
          a[j + sz] = cmulv(v, B[w]);
        }
      }
    }
    // Phi-corrected physical store addresses
    unsigned dw = 0;
    #pragma unroll
    for (int j = 0; j < 4; ++j)
      dw ^= ((t >> (6 + j)) & 1u) ? (unsigned)C.dcolw[j] : 0u;
    #pragma unroll
    for (int e = 0; e < 16; ++e)
      st[(((unsigned)e << 10) | (unsigned)t) ^ (unsigned)C.de[e] ^ dw] = a[e];
  }
  __syncthreads();

  // ---- layers 1..7, two 7-wire tangent passes each
  #pragma unroll 1
  for (int d = 1; d <= 6; ++d) {
    const float* th = theta + d * NQ;
    const float2* tqd = USE_WS ? (tq + d * NQ) : nullptr;
    ry7x<USE_WS, true>(st, C.pass[(d - 1) * 2 + 0], th, tqd, t, a);
    __syncthreads();
    ry7x<USE_WS, true>(st, C.pass[(d - 1) * 2 + 1], th, tqd, t, a);
    __syncthreads();
  }
  {
    const float* th = theta + 7 * NQ;
    const float2* tqd = USE_WS ? (tq + 7 * NQ) : nullptr;
    ry7x<USE_WS, true>(st, C.pass[12], th, tqd, t, a);
    __syncthreads();
    // last pass: keep results in registers, fuse measurement
    ry7x<USE_WS, false>(st, C.pass[13], th, tqd, t, a);
  }
  __syncthreads();   // all reads of the final pass done before st is reused

  // ---- measurement: per-thread |amp|^2, 4-bit WHT in mask basis
  float pv[16];
  #pragma unroll
  for (int e = 0; e < 16; ++e) pv[e] = a[e].x * a[e].x + a[e].y * a[e].y;
  #pragma unroll
  for (int s4 = 0; s4 < 4; ++s4) {
    const int step = 1 << s4;
    #pragma unroll
    for (int e = 0; e < 16; ++e) {
      if (!(e & step)) {
        float x = pv[e], y = pv[e | step];
        pv[e] = x + y; pv[e | step] = x - y;
      }
    }
  }
  float* stf = (float*)st;
  #pragma unroll
  for (int e = 0; e < 16; ++e) stf[(e << 10) | t] = pv[e];
  __syncthreads();

  float acc[NQ];
  #pragma unroll
  for (int w = 0; w < NQ; ++w) {
    const unsigned zf = (unsigned)C.zfreq[w];
    float v = stf[(zf << 10) | (unsigned)t];
    acc[w] = (__popc((unsigned)C.zm[w] & (unsigned)t) & 1) ? -v : v;
  }
  #pragma unroll
  for (int w = 0; w < NQ; ++w) {
    #pragma unroll
    for (int off = 32; off > 0; off >>= 1)
      acc[w] += __shfl_xor(acc[w], off, 64);
  }
  __syncthreads();
  const int lane = t & 63, wid = t >> 6;   // wid in 0..15
  if (lane == 0) {
    #pragma unroll
    for (int w = 0; w < NQ; ++w) stf[wid * NQ + w] = acc[w];
  }
  __syncthreads();
  if (t < NQ) {
    float tot = 0.f;
    #pragma unroll
    for (int k = 0; k < 16; ++k) tot += stf[k * NQ + t];
    float s2v;
    if constexpr (USE_WS) {
      s2v = *s2p;
    } else {
      double pr = 1.0;
      for (int j = NQ; j < DEPTH * NQ; ++j) {
        float ss, cc; sincosf(0.5f * theta[j], &ss, &cc);
        pr *= (double)cc * (double)cc;
      }
      s2v = (float)pr;
    }
    out[s * NQ + t] = tot * s2v;
  }
}

// ---------- prep: precise trig tables + deferred-scale into workspace ----------
// ws float layout: [0,224) tt (c,s) pairs; [256,480) tq (t,c) pairs; [512] S^2
__global__ void prep_kernel(const float* __restrict__ inp,
                            const float* __restrict__ theta,
                            float* __restrict__ ws, float4* __restrict__ albe,
                            int nAlbe) {
  const int i = blockIdx.x * 256 + threadIdx.x;
  float2* tt = (float2*)ws;
  float2* tq = (float2*)(ws + 256);
  if (i < DEPTH * NQ) {
    float ss, cc; sincosf(0.5f * theta[i], &ss, &cc);
    tt[i] = make_float2(cc, ss);
    float ca = (fabsf(cc) < 1e-20f) ? copysignf(1e-20f, cc) : cc;
    tq[i] = make_float2(ss / ca, ca);
  }
  if (i == 0) {
    double pr = 1.0;
    for (int j = NQ; j < DEPTH * NQ; ++j) {
      double cc = cos(0.5 * (double)theta[j]);
      pr *= cc * cc;
    }
    ws[512] = (float)pr;
  }
  if (albe != nullptr && i < nAlbe) {
    const int w = i % NQ;
    float sx, cx; sincosf(0.5f * inp[i], &sx, &cx);
    float stt, ctt; sincosf(0.5f * theta[w], &stt, &ctt);
    albe[i] = make_float4(ctt * cx, stt * sx, stt * cx, -ctt * sx);
  }
}

// ---------- host: GF(2) linear algebra for the CNOT-ring permutation ----------
static inline unsigned ffwd(unsigned x) {
  unsigned t = x;
  t ^= t >> 1; t ^= t >> 2; t ^= t >> 4; t ^= t >> 8;
  unsigned y = t & 0x1FFFu;
  y |= (((t >> 13) ^ t) & 1u) << 13;
  return y;
}
static inline unsigned finv(unsigned y) {
  unsigned x = 0;
  for (int j = 0; j <= 11; ++j) x |= (((y >> j) ^ (y >> (j + 1))) & 1u) << j;
  x |= (((y >> 12) ^ (y >> 13) ^ y) & 1u) << 12;
  x |= (((y >> 13) ^ y) & 1u) << 13;
  return x;
}
static inline int rank3n(unsigned a, unsigned b, unsigned c) {
  unsigned bas[4] = {0, 0, 0, 0};
  unsigned vv[3] = {a & 15u, b & 15u, c & 15u};
  int r = 0;
  for (int i = 0; i < 3; ++i) {
    unsigned u = vv[i];
    for (int bit = 3; bit >= 0; --bit)
      if (((u >> bit) & 1u) && bas[bit]) u ^= bas[bit];
    if (u) { bas[31 - __builtin_clz(u)] = u; ++r; }
  }
  return r;
}
static inline unsigned phi_full(unsigned m, const unsigned* ac) {
  unsigned d = 0;
  for (int j = 0; j < 8; ++j)
    if ((m >> (6 + j)) & 1u) d ^= ac[j];
  return m ^ d;
}
static inline int par(unsigned x) { return __builtin_popcount(x) & 1; }

static int scoreA(const unsigned* ac, const u16 am[14][7], int bail) {
  int s = 0;
  for (int p = 0; p < 14; ++p) {
    unsigned pm[7];
    for (int i = 0; i < 7; ++i) pm[i] = phi_full((unsigned)am[p][i], ac) & 15u;
    int best = 0;
    for (int x = 0; x < 7 && best < 3; ++x)
      for (int y = x + 1; y < 7 && best < 3; ++y)
        for (int z = y + 1; z < 7 && best < 3; ++z) {
          int r = rank3n(pm[x], pm[y], pm[z]);
          if (r > best) best = r;
        }
    if (best < 3) s += 3 - best;
    if (s >= bail) return s;
  }
  return s;
}

extern "C" void kernel_launch(void* const* d_in, const int* in_sizes, int n_in,
                              void* d_out, int out_size, void* d_ws, size_t ws_size,
                              hipStream_t stream) {
  const float* inp = (const float*)d_in[0];
  const float* theta = (const float*)d_in[1];
  float* out = (float*)d_out;
  const int batch = in_sizes[0] / NQ;

  // ---- collect per-pass wire masks (K cols) and sign rows (L rows)
  u16 Lc[NQ], Kc[NQ];
  u16 allmask[14][7]; unsigned allrow[14][7];
  u16 zrow[NQ];
  for (int j = 0; j < NQ; ++j) { Lc[j] = (u16)(1u << j); Kc[j] = (u16)(1u << j); }
  for (int d = 1; d <= 8; ++d) {
    u16 nL[NQ], nK[NQ];
    for (int j = 0; j < NQ; ++j) nL[j] = (u16)ffwd((unsigned)Lc[j]);
    for (int j = 0; j < NQ; ++j) {
      unsigned fj = finv(1u << j);
      unsigned v = 0;
      for (int b = 0; b < NQ; ++b) if ((fj >> b) & 1u) v ^= Kc[b];
      nK[j] = (u16)v;
    }
    for (int j = 0; j < NQ; ++j) { Lc[j] = nL[j]; Kc[j] = nK[j]; }

    if (d <= 7) {
      for (int pg = 0; pg < 2; ++pg) {
        const int p = (d - 1) * 2 + pg;
        const int wbase = pg * 7;
        for (int i = 0; i < 7; ++i) {
          const int bit = 13 - (wbase + i);
          allmask[p][i] = Kc[bit];
          unsigned r = 0;
          for (int j = 0; j < NQ; ++j) r |= ((unsigned)(Lc[j] >> bit) & 1u) << j;
          allrow[p][i] = r;
        }
      }
    } else {
      for (int w = 0; w < NQ; ++w) {
        const int bit = 13 - w;
        unsigned r = 0;
        for (int j = 0; j < NQ; ++j) r |= ((unsigned)(Lc[j] >> bit) & 1u) << j;
        zrow[w] = (u16)r;
      }
    }
  }

  // ---- search layout map A (8 cols -> low4) so every pass has a rank-3 triple
  unsigned acol[8] = {0, 0, 0, 0, 0, 0, 0, 0};
  int bestSc = scoreA(acol, allmask, 1 << 30);
  if (bestSc > 0) {
    unsigned long long seed = 88172645463325252ULL;
    for (int it = 0; it < 20000 && bestSc > 0; ++it) {
      unsigned cand[8];
      for (int j = 0; j < 8; ++j) {
        seed ^= seed << 13; seed ^= seed >> 7; seed ^= seed << 17;
        cand[j] = (unsigned)(seed & 15u);
      }
      int sc = scoreA(cand, allmask, bestSc);
      if (sc < bestSc) {
        bestSc = sc;
        for (int j = 0; j < 8; ++j) acol[j] = cand[j];
      }
    }
  }

  // ---- build pass constants
  SimConsts C;
  u16 mkLast[4] = {0, 0, 0, 0};
  unsigned lcolLast[10] = {0};
  for (int p = 0; p < 14; ++p) {
    PassK& P = C.pass[p];
    const int pg = p & 1, wbase = pg * 7;

    unsigned pm[7];
    for (int i = 0; i < 7; ++i) pm[i] = phi_full((unsigned)allmask[p][i], acol) & 15u;
    int ca = 0, cb = 1, cc2 = 2, best = -1;
    for (int x = 0; x < 7; ++x)
      for (int y = x + 1; y < 7; ++y)
        for (int z = y + 1; z < 7; ++z) {
          int r = rank3n(pm[x], pm[y], pm[z]);
          if (r > best) { best = r; ca = x; cb = y; cc2 = z; }
        }

    unsigned cmL[3] = {allmask[p][ca], allmask[p][cb], allmask[p][cc2]};
    unsigned srowAll[7];
    srowAll[4] = allrow[p][ca]; srowAll[5] = allrow[p][cb]; srowAll[6] = allrow[p][cc2];
    P.widx[4] = (u16)(wbase + ca); P.widx[5] = (u16)(wbase + cb);
    P.widx[6] = (u16)(wbase + cc2);
    u16 mk[4]; int ii = 0;
    for (int i = 0; i < 7; ++i)
      if (i != ca && i != cb && i != cc2) {
        mk[ii] = allmask[p][i]; srowAll[ii] = allrow[p][i];
        P.widx[ii] = (u16)(wbase + i); ++ii;
      }
    if (p == 13) for (int i = 0; i < 4; ++i) mkLast[i] = mk[i];

    // full-rank (14-dim) independence tracker
    unsigned red[14] = {0};
    auto tryAdd = [&](unsigned x) -> bool {
      while (x) {
        int h = 31 - __builtin_clz(x);
        if (!red[h]) { red[h] = x; return true; }
        x ^= red[h];
      }
      return false;
    };
    for (int i = 0; i < 7; ++i) tryAdd((unsigned)allmask[p][i]);

    // physical low4 span of the cross triple
    unsigned nb[4] = {0, 0, 0, 0};
    for (int i = 0; i < 3; ++i) {
      unsigned u = pm[i == 0 ? ca : (i == 1 ? cb : cc2)];
      for (int bit = 3; bit >= 0; --bit)
        if (((u >> bit) & 1u) && nb[bit]) u ^= nb[bit];
      if (u) nb[31 - __builtin_clz(u)] = u;
    }
    // target low4 for scol0: smallest value outside the span
    unsigned uTarget = 0;
    for (unsigned v = 1; v < 16; ++v) {
      unsigned r = v;
      for (int bit = 3; bit >= 0; --bit)
        if (((r >> bit) & 1u) && nb[bit]) r ^= nb[bit];
      if (r) { uTarget = v; break; }
    }
    unsigned scol[7];
    {
      bool ok = false;
      for (unsigned h = 0; h < 256u && !ok; ++h) {
        unsigned d4 = 0;
        for (int j = 0; j < 8; ++j) if ((h >> j) & 1u) d4 ^= acol[j];
        unsigned v = ((uTarget ^ d4) & 15u) | (h << 6);
        if (v && tryAdd(v)) { scol[0] = v; ok = true; }
      }
      for (unsigned cand = 1; cand < 16384u && !ok; ++cand)
        if (tryAdd(cand)) { scol[0] = cand; ok = true; }
    }
    for (int i2 = 1; i2 < 7; ++i2) {
      bool ok = false;
      for (unsigned h = 1; h < 256u && !ok; ++h)
        if (tryAdd(h << 6)) { scol[i2] = h << 6; ok = true; }
      for (unsigned cand = 1; cand < 16384u && !ok; ++cand)
        if (tryAdd(cand)) { scol[i2] = cand; ok = true; }
    }

    unsigned lcol[10] = {cmL[0], cmL[1], scol[0], cmL[2],
                         scol[1], scol[2], scol[3], scol[4], scol[5], scol[6]};
    for (int b = 0; b < 10; ++b) P.pcol[b] = (u16)phi_full(lcol[b], acol);
    if (p == 13) for (int b = 0; b < 10; ++b) lcolLast[b] = lcol[b];

    for (int i = 0; i < 7; ++i) {
      unsigned m = 0;
      for (int b = 0; b < 10; ++b)
        m |= (unsigned)par(srowAll[i] & lcol[b]) << b;
      P.sm[i] = (u16)m;
    }
    for (int e = 0; e < 16; ++e) {
      unsigned v = 0;
      for (int i = 0; i < 4; ++i)
        if ((e >> i) & 1) v ^= (unsigned)mk[i];
      P.pxm[e] = (u16)phi_full(v, acol);
    }
  }

  // measurement constants (last-pass basis)
  for (int w = 0; w < NQ; ++w) {
    unsigned zf = 0;
    for (int i = 0; i < 4; ++i)
      zf |= (unsigned)par((unsigned)zrow[w] & (unsigned)mkLast[i]) << i;
    C.zfreq[w] = (u16)zf;
    unsigned m = 0;
    for (int b = 0; b < 10; ++b)
      m |= (unsigned)par((unsigned)zrow[w] & lcolLast[b]) << b;
    C.zm[w] = (u16)m;
  }
  // init-write Phi deltas
  for (int e = 0; e < 16; ++e) {
    unsigned d4 = 0;
    for (int k = 0; k < 4; ++k)
      if ((e >> k) & 1) d4 ^= acol[4 + k];
    C.de[e] = (u16)d4;
  }
  for (int j = 0; j < 4; ++j) C.dcolw[j] = (u16)acol[j];

  // ws float layout: [0,224) tt; [256,480) tq; [512] S2; albe from byte 4096
  const size_t needT = 4096;
  const size_t needA = 4096 + (size_t)batch * NQ * sizeof(float4);
  const bool useT = ws_size >= needT;
  const bool useA = useT && ws_size >= needA;
  float* wsf = (float*)d_ws;
  float2* tt = (float2*)wsf;
  float2* tq = (float2*)(wsf + 256);
  float* s2p = wsf + 512;
  float4* albe = (float4*)((char*)d_ws + 4096);

  if (useT) {
    const int nAlbe = useA ? batch * NQ : 0;
    const int nwork = useA ? nAlbe : DEPTH * NQ;
    prep_kernel<<<(nwork + 255) / 256, 256, 0, stream>>>(
        inp, theta, wsf, useA ? albe : nullptr, nAlbe);
    qsim_kernel<true><<<batch, TPB, 0, stream>>>(inp, theta, out, tt, tq, s2p,
                                                 albe, useA ? 1 : 0, C);
  } else {
    qsim_kernel<false><<<batch, TPB, 0, stream>>>(inp, theta, out, nullptr,
                                                  nullptr, nullptr, nullptr, 0, C);
  }
}